// Round 1
// baseline (3315.614 us; speedup 1.0000x reference)
//
#include <hip/hip_runtime.h>
#include <math.h>

#define N_USERS 100000
#define N_ITEMS 200000
#define NTOT    300000
#define NEDGE   1200000
#define DIM     64

// Workspace layout (floats):
//   emb1    : [0,            NTOT*DIM)        -- GCN layer1 out; later reused as K
//   emb2    : [NTOT*DIM,     2*NTOT*DIM)      -- GCN layer2 out; later overwritten in-place by V
//   Q       : [2*NTOT*DIM,   3*NTOT*DIM)
//   attNorm : [3*NTOT*DIM,   +NTOT*4)
//   expAtt  : [...,          +NEDGE*4)
// total ~255 MB

__device__ __forceinline__ void atomAddF(float* p, float v) {
    unsafeAtomicAdd(p, v);   // native global_atomic_add_f32 on gfx950
}

// ---------------- GCN spmm: dst[rows[e]] += vals[e] * src[cols[e]] ----------
// 16 threads per edge, float4 per thread. iE==nullptr -> single table src=uE.
__global__ __launch_bounds__(256) void gcn_kernel(
    const float* __restrict__ vals, const int* __restrict__ rows,
    const int* __restrict__ cols, const float* __restrict__ uE,
    const float* __restrict__ iE, float* __restrict__ dst) {
    int t = blockIdx.x * 256 + threadIdx.x;
    int e = t >> 4, l = t & 15;
    if (e >= NEDGE) return;
    int row = rows[e], col = cols[e];
    float val = vals[e];
    const float* src;
    if (iE) src = (col < N_USERS) ? (uE + (size_t)col * DIM)
                                  : (iE + (size_t)(col - N_USERS) * DIM);
    else    src = uE + (size_t)col * DIM;
    float4 x = reinterpret_cast<const float4*>(src)[l];
    float* dp = dst + (size_t)row * DIM + l * 4;
    atomAddF(dp + 0, val * x.x);
    atomAddF(dp + 1, val * x.y);
    atomAddF(dp + 2, val * x.z);
    atomAddF(dp + 3, val * x.w);
}

// ---------------- out = concat(uE,iE) + emb1 + emb2 (per float4) ------------
__global__ __launch_bounds__(256) void sum_kernel(
    const float* __restrict__ uE, const float* __restrict__ iE,
    const float* __restrict__ e1, const float* __restrict__ e2,
    float* __restrict__ out) {
    int i = blockIdx.x * 256 + threadIdx.x;   // float4 index over NTOT*16
    if (i >= NTOT * 16) return;
    float4 a = (i < N_USERS * 16) ? reinterpret_cast<const float4*>(uE)[i]
                                  : reinterpret_cast<const float4*>(iE)[i - N_USERS * 16];
    float4 b = reinterpret_cast<const float4*>(e1)[i];
    float4 c = reinterpret_cast<const float4*>(e2)[i];
    float4 o;
    o.x = a.x + b.x + c.x; o.y = a.y + b.y + c.y;
    o.z = a.z + b.z + c.z; o.w = a.w + b.w + c.w;
    reinterpret_cast<float4*>(out)[i] = o;
}

// ---------------- fused Q/K/V = emb2 @ {qT,kT,vT} ---------------------------
// One block = 64 rows. A-tile staged transposed in LDS; B matrices in LDS.
// V written in-place over emb2 (rows fully read into LDS before stores).
__global__ __launch_bounds__(256) void qkv_kernel(
    const float* __restrict__ emb2, const float* __restrict__ qT,
    const float* __restrict__ kT, const float* __restrict__ vT,
    float* __restrict__ Q, float* __restrict__ K, float* __restrict__ V) {
    __shared__ float lds[4 * 4096];   // 64 KB: a_t | bq | bk | bv
    float* a_t = lds;
    float* bq = lds + 4096;
    float* bk = lds + 8192;
    float* bv = lds + 12288;
    int t = threadIdx.x;
    int R0 = blockIdx.x * 64;

    // stage B matrices (each 4096 floats = 1024 float4)
    {
        const float4* q4 = reinterpret_cast<const float4*>(qT);
        const float4* k4 = reinterpret_cast<const float4*>(kT);
        const float4* v4 = reinterpret_cast<const float4*>(vT);
        float4* lq = reinterpret_cast<float4*>(bq);
        float4* lk = reinterpret_cast<float4*>(bk);
        float4* lv = reinterpret_cast<float4*>(bv);
#pragma unroll
        for (int k = 0; k < 4; ++k) {
            lq[t + k * 256] = q4[t + k * 256];
            lk[t + k * 256] = k4[t + k * 256];
            lv[t + k * 256] = v4[t + k * 256];
        }
    }
    // stage A transposed: a_t[i][r] = emb2[R0+r][i]
    {
        int r = t >> 2, qt = t & 3;
        int grow = R0 + r;
        const float4* src = reinterpret_cast<const float4*>(emb2 + (size_t)grow * DIM);
        bool ok = (grow < NTOT);
#pragma unroll
        for (int k = 0; k < 4; ++k) {
            float4 x;
            if (ok) x = src[qt * 4 + k];
            else { x.x = x.y = x.z = x.w = 0.f; }
            int i0 = qt * 16 + k * 4;
            a_t[(i0 + 0) * 64 + r] = x.x;
            a_t[(i0 + 1) * 64 + r] = x.y;
            a_t[(i0 + 2) * 64 + r] = x.z;
            a_t[(i0 + 3) * 64 + r] = x.w;
        }
    }
    __syncthreads();

    int ty = t >> 4, tx = t & 15;
    float cq[4][4] = {}, ck[4][4] = {}, cv[4][4] = {};
#pragma unroll 4
    for (int i = 0; i < 64; ++i) {
        float4 a = *reinterpret_cast<const float4*>(&a_t[i * 64 + ty * 4]);
        float4 q = *reinterpret_cast<const float4*>(&bq[i * 64 + tx * 4]);
        float4 k = *reinterpret_cast<const float4*>(&bk[i * 64 + tx * 4]);
        float4 v = *reinterpret_cast<const float4*>(&bv[i * 64 + tx * 4]);
        float av[4] = {a.x, a.y, a.z, a.w};
        float qv[4] = {q.x, q.y, q.z, q.w};
        float kv[4] = {k.x, k.y, k.z, k.w};
        float vv[4] = {v.x, v.y, v.z, v.w};
#pragma unroll
        for (int r = 0; r < 4; ++r) {
#pragma unroll
            for (int c = 0; c < 4; ++c) {
                cq[r][c] += av[r] * qv[c];
                ck[r][c] += av[r] * kv[c];
                cv[r][c] += av[r] * vv[c];
            }
        }
    }
    __syncthreads();

#pragma unroll
    for (int r = 0; r < 4; ++r) {
        int grow = R0 + ty * 4 + r;
        if (grow >= NTOT) continue;
        float4 sq, sk, sv;
        sq.x = cq[r][0]; sq.y = cq[r][1]; sq.z = cq[r][2]; sq.w = cq[r][3];
        sk.x = ck[r][0]; sk.y = ck[r][1]; sk.z = ck[r][2]; sk.w = ck[r][3];
        sv.x = cv[r][0]; sv.y = cv[r][1]; sv.z = cv[r][2]; sv.w = cv[r][3];
        reinterpret_cast<float4*>(Q + (size_t)grow * DIM)[tx] = sq;
        reinterpret_cast<float4*>(K + (size_t)grow * DIM)[tx] = sk;
        reinterpret_cast<float4*>(V + (size_t)grow * DIM)[tx] = sv;
    }
}

// ---------------- GT pass 1: expAtt + attNorm -------------------------------
// 16 threads per edge; head h = l>>2; 4-lane butterfly for per-head dot.
__global__ __launch_bounds__(256) void gt_pass1(
    const int* __restrict__ rows, const int* __restrict__ cols,
    const float* __restrict__ Q, const float* __restrict__ K,
    float* __restrict__ attNorm, float* __restrict__ expAtt) {
    int t = blockIdx.x * 256 + threadIdx.x;
    int e = t >> 4, l = t & 15;
    if (e >= NEDGE) return;
    int row = rows[e], col = cols[e];
    float4 q = reinterpret_cast<const float4*>(Q)[(size_t)row * 16 + l];
    float4 k = reinterpret_cast<const float4*>(K)[(size_t)col * 16 + l];
    float p = q.x * k.x + q.y * k.y + q.z * k.z + q.w * k.w;
    p += __shfl_xor(p, 1);
    p += __shfl_xor(p, 2);
    if ((l & 3) == 0) {
        float att = fminf(10.f, fmaxf(-10.f, p));
        float ex = expf(att);
        int h = l >> 2;
        expAtt[(size_t)e * 4 + h] = ex;
        atomAddF(&attNorm[(size_t)row * 4 + h], ex);
    }
}

// ---------------- GT pass 2: out[row] += a * V[col] -------------------------
__global__ __launch_bounds__(256) void gt_pass2(
    const int* __restrict__ rows, const int* __restrict__ cols,
    const float* __restrict__ V, const float* __restrict__ attNorm,
    const float* __restrict__ expAtt, float* __restrict__ out) {
    int t = blockIdx.x * 256 + threadIdx.x;
    int e = t >> 4, l = t & 15;
    if (e >= NEDGE) return;
    int row = rows[e], col = cols[e];
    int h = l >> 2;
    float ex = expAtt[(size_t)e * 4 + h];
    float nrm = attNorm[(size_t)row * 4 + h];
    float a = ex / (nrm + 1e-8f);
    float4 v = reinterpret_cast<const float4*>(V)[(size_t)col * 16 + l];
    float* dp = out + (size_t)row * DIM + l * 4;
    atomAddF(dp + 0, a * v.x);
    atomAddF(dp + 1, a * v.y);
    atomAddF(dp + 2, a * v.z);
    atomAddF(dp + 3, a * v.w);
}

extern "C" void kernel_launch(void* const* d_in, const int* in_sizes, int n_in,
                              void* d_out, int out_size, void* d_ws, size_t ws_size,
                              hipStream_t stream) {
    const float* uE       = (const float*)d_in[0];
    const float* iE       = (const float*)d_in[1];
    const float* qT       = (const float*)d_in[2];
    const float* kT       = (const float*)d_in[3];
    const float* vT       = (const float*)d_in[4];
    const float* enc_vals = (const float*)d_in[5];
    const int*   enc_rows = (const int*)d_in[6];
    const int*   enc_cols = (const int*)d_in[7];
    const int*   dec_rows = (const int*)d_in[8];
    const int*   dec_cols = (const int*)d_in[9];
    float* out = (float*)d_out;

    float* ws   = (float*)d_ws;
    const size_t ND = (size_t)NTOT * DIM;
    float* emb1 = ws;
    float* emb2 = ws + ND;
    float* Q    = ws + 2 * ND;
    float* attN = ws + 3 * ND;
    float* expA = attN + (size_t)NTOT * 4;
    float* K    = emb1;   // reused after sum_kernel consumed emb1
    float* V    = emb2;   // in-place over emb2 (safe: qkv blocks read own rows first)

    hipMemsetAsync(emb1, 0, 2 * ND * sizeof(float), stream);          // emb1+emb2
    hipMemsetAsync(attN, 0, (size_t)NTOT * 4 * sizeof(float), stream);

    const int EB = (NEDGE * 16) / 256;        // 75000 blocks
    const int SB = (NTOT * 16) / 256;         // 18750 blocks
    const int QB = (NTOT + 63) / 64;          // 4688 blocks

    gcn_kernel<<<EB, 256, 0, stream>>>(enc_vals, enc_rows, enc_cols, uE, iE, emb1);
    gcn_kernel<<<EB, 256, 0, stream>>>(enc_vals, enc_rows, enc_cols, emb1, nullptr, emb2);
    sum_kernel<<<SB, 256, 0, stream>>>(uE, iE, emb1, emb2, out);
    qkv_kernel<<<QB, 256, 0, stream>>>(emb2, qT, kT, vT, Q, K, V);
    gt_pass1<<<EB, 256, 0, stream>>>(dec_rows, dec_cols, Q, K, attN, expA);
    gt_pass2<<<EB, 256, 0, stream>>>(dec_rows, dec_cols, V, attN, expA, out);
}

// Round 2
// 726.714 us; speedup vs baseline: 4.5625x; 4.5625x over previous
//
#include <hip/hip_runtime.h>
#include <math.h>

#define N_USERS 100000
#define NTOT    300000
#define NEDGE   1200000
#define DIM     64
#define SCAN_CHUNK 1024
#define NSCAN_BLK ((NTOT + SCAN_CHUNK - 1) / SCAN_CHUNK)   // 293

// Workspace layout (floats / ints), total ~247 MB (< round-1's working 254 MB):
//   emb1   : ND floats (76.8 MB)  -- GCN L1 out; later reused as K
//   emb2   : ND floats            -- GCN L2 out; overwritten in-place by V
//   Q      : ND floats
//   cursorE: NTOT ints   (counts -> exclusive prefix -> end offsets after scatter)
//   pcolE  : NEDGE ints
//   pvalE  : NEDGE floats
//   cursorD: NTOT ints
//   pcolD  : NEDGE ints
//   bsum   : 512 ints (scan temp)

// ---------------- CSR build -------------------------------------------------
__global__ __launch_bounds__(256) void hist_kernel(const int* __restrict__ rows,
                                                   int* __restrict__ cnt) {
    int e = blockIdx.x * 256 + threadIdx.x;
    if (e < NEDGE) atomicAdd(&cnt[rows[e]], 1);
}

__global__ __launch_bounds__(256) void scan1(const int* __restrict__ cnt,
                                             int* __restrict__ bsum) {
    __shared__ int sh[256];
    int b = blockIdx.x, t = threadIdx.x;
    int base = b * SCAN_CHUNK + t * 4;
    int s = 0;
#pragma unroll
    for (int i = 0; i < 4; ++i) { int idx = base + i; if (idx < NTOT) s += cnt[idx]; }
    sh[t] = s; __syncthreads();
    for (int off = 1; off < 256; off <<= 1) {
        int x = (t >= off) ? sh[t - off] : 0; __syncthreads();
        sh[t] += x; __syncthreads();
    }
    if (t == 255) bsum[b] = sh[255];
}

__global__ __launch_bounds__(512) void scan2(int* __restrict__ bsum) {
    __shared__ int sh[512];
    int t = threadIdx.x;
    int v = (t < NSCAN_BLK) ? bsum[t] : 0;
    sh[t] = v; __syncthreads();
    for (int off = 1; off < 512; off <<= 1) {
        int x = (t >= off) ? sh[t - off] : 0; __syncthreads();
        sh[t] += x; __syncthreads();
    }
    if (t < NSCAN_BLK) bsum[t] = sh[t] - v;   // exclusive
}

__global__ __launch_bounds__(256) void scan3(int* __restrict__ cnt,
                                             const int* __restrict__ bsum) {
    __shared__ int sh[256];
    int b = blockIdx.x, t = threadIdx.x;
    int base = b * SCAN_CHUNK + t * 4;
    int c[4]; int s = 0;
#pragma unroll
    for (int i = 0; i < 4; ++i) { int idx = base + i; c[i] = (idx < NTOT) ? cnt[idx] : 0; s += c[i]; }
    sh[t] = s; __syncthreads();
    for (int off = 1; off < 256; off <<= 1) {
        int x = (t >= off) ? sh[t - off] : 0; __syncthreads();
        sh[t] += x; __syncthreads();
    }
    int excl = sh[t] - s + bsum[b];
#pragma unroll
    for (int i = 0; i < 4; ++i) {
        int idx = base + i;
        if (idx < NTOT) { cnt[idx] = excl; excl += c[i]; }
    }
}

__global__ __launch_bounds__(256) void scatter_enc(
    const int* __restrict__ rows, const int* __restrict__ cols,
    const float* __restrict__ vals, int* __restrict__ cursor,
    int* __restrict__ pcol, float* __restrict__ pval) {
    int e = blockIdx.x * 256 + threadIdx.x;
    if (e >= NEDGE) return;
    int pos = atomicAdd(&cursor[rows[e]], 1);
    pcol[pos] = cols[e];
    pval[pos] = vals[e];
}

__global__ __launch_bounds__(256) void scatter_dec(
    const int* __restrict__ rows, const int* __restrict__ cols,
    int* __restrict__ cursor, int* __restrict__ pcol) {
    int e = blockIdx.x * 256 + threadIdx.x;
    if (e >= NEDGE) return;
    int pos = atomicAdd(&cursor[rows[e]], 1);
    pcol[pos] = cols[e];
}

// ---------------- GCN spmm as gather: dst[r] = sum_e val*src[col] -----------
// After scatter: cursor[r] = rowPtr[r+1]; start(r) = r ? cursor[r-1] : 0.
__global__ __launch_bounds__(256) void gcn_gather(
    const int* __restrict__ cursor, const int* __restrict__ pcol,
    const float* __restrict__ pval, const float* __restrict__ uE,
    const float* __restrict__ iE, float* __restrict__ dst) {
    int t = blockIdx.x * 256 + threadIdx.x;
    int row = t >> 4, l = t & 15;
    if (row >= NTOT) return;
    int s = (row == 0) ? 0 : cursor[row - 1];
    int e = cursor[row];
    float4 acc = {0.f, 0.f, 0.f, 0.f};
    for (int j = s; j < e; ++j) {
        int c = pcol[j];
        float v = pval[j];
        const float* src = iE ? ((c < N_USERS) ? uE + (size_t)c * DIM
                                               : iE + (size_t)(c - N_USERS) * DIM)
                              : uE + (size_t)c * DIM;
        float4 x = reinterpret_cast<const float4*>(src)[l];
        acc.x += v * x.x; acc.y += v * x.y; acc.z += v * x.z; acc.w += v * x.w;
    }
    reinterpret_cast<float4*>(dst)[(size_t)row * 16 + l] = acc;
}

// ---------------- out = concat(uE,iE) + emb1 + emb2 -------------------------
__global__ __launch_bounds__(256) void sum_kernel(
    const float* __restrict__ uE, const float* __restrict__ iE,
    const float* __restrict__ e1, const float* __restrict__ e2,
    float* __restrict__ out) {
    int i = blockIdx.x * 256 + threadIdx.x;
    if (i >= NTOT * 16) return;
    float4 a = (i < N_USERS * 16) ? reinterpret_cast<const float4*>(uE)[i]
                                  : reinterpret_cast<const float4*>(iE)[i - N_USERS * 16];
    float4 b = reinterpret_cast<const float4*>(e1)[i];
    float4 c = reinterpret_cast<const float4*>(e2)[i];
    float4 o;
    o.x = a.x + b.x + c.x; o.y = a.y + b.y + c.y;
    o.z = a.z + b.z + c.z; o.w = a.w + b.w + c.w;
    reinterpret_cast<float4*>(out)[i] = o;
}

// ---------------- fused Q/K/V = emb2 @ {qT,kT,vT} ---------------------------
__global__ __launch_bounds__(256) void qkv_kernel(
    const float* __restrict__ emb2, const float* __restrict__ qT,
    const float* __restrict__ kT, const float* __restrict__ vT,
    float* __restrict__ Q, float* __restrict__ K, float* __restrict__ V) {
    __shared__ float lds[4 * 4096];
    float* a_t = lds;
    float* bq = lds + 4096;
    float* bk = lds + 8192;
    float* bv = lds + 12288;
    int t = threadIdx.x;
    int R0 = blockIdx.x * 64;

    {
        const float4* q4 = reinterpret_cast<const float4*>(qT);
        const float4* k4 = reinterpret_cast<const float4*>(kT);
        const float4* v4 = reinterpret_cast<const float4*>(vT);
        float4* lq = reinterpret_cast<float4*>(bq);
        float4* lk = reinterpret_cast<float4*>(bk);
        float4* lv = reinterpret_cast<float4*>(bv);
#pragma unroll
        for (int k = 0; k < 4; ++k) {
            lq[t + k * 256] = q4[t + k * 256];
            lk[t + k * 256] = k4[t + k * 256];
            lv[t + k * 256] = v4[t + k * 256];
        }
    }
    {
        int r = t >> 2, qt = t & 3;
        int grow = R0 + r;
        const float4* src = reinterpret_cast<const float4*>(emb2 + (size_t)grow * DIM);
        bool ok = (grow < NTOT);
#pragma unroll
        for (int k = 0; k < 4; ++k) {
            float4 x;
            if (ok) x = src[qt * 4 + k];
            else { x.x = x.y = x.z = x.w = 0.f; }
            int i0 = qt * 16 + k * 4;
            a_t[(i0 + 0) * 64 + r] = x.x;
            a_t[(i0 + 1) * 64 + r] = x.y;
            a_t[(i0 + 2) * 64 + r] = x.z;
            a_t[(i0 + 3) * 64 + r] = x.w;
        }
    }
    __syncthreads();

    int ty = t >> 4, tx = t & 15;
    float cq[4][4] = {}, ck[4][4] = {}, cv[4][4] = {};
#pragma unroll 4
    for (int i = 0; i < 64; ++i) {
        float4 a = *reinterpret_cast<const float4*>(&a_t[i * 64 + ty * 4]);
        float4 q = *reinterpret_cast<const float4*>(&bq[i * 64 + tx * 4]);
        float4 k = *reinterpret_cast<const float4*>(&bk[i * 64 + tx * 4]);
        float4 v = *reinterpret_cast<const float4*>(&bv[i * 64 + tx * 4]);
        float av[4] = {a.x, a.y, a.z, a.w};
        float qv[4] = {q.x, q.y, q.z, q.w};
        float kv[4] = {k.x, k.y, k.z, k.w};
        float vv[4] = {v.x, v.y, v.z, v.w};
#pragma unroll
        for (int r = 0; r < 4; ++r) {
#pragma unroll
            for (int c = 0; c < 4; ++c) {
                cq[r][c] += av[r] * qv[c];
                ck[r][c] += av[r] * kv[c];
                cv[r][c] += av[r] * vv[c];
            }
        }
    }
    __syncthreads();

#pragma unroll
    for (int r = 0; r < 4; ++r) {
        int grow = R0 + ty * 4 + r;
        if (grow >= NTOT) continue;
        float4 sq, sk, sv;
        sq.x = cq[r][0]; sq.y = cq[r][1]; sq.z = cq[r][2]; sq.w = cq[r][3];
        sk.x = ck[r][0]; sk.y = ck[r][1]; sk.z = ck[r][2]; sk.w = ck[r][3];
        sv.x = cv[r][0]; sv.y = cv[r][1]; sv.z = cv[r][2]; sv.w = cv[r][3];
        reinterpret_cast<float4*>(Q + (size_t)grow * DIM)[tx] = sq;
        reinterpret_cast<float4*>(K + (size_t)grow * DIM)[tx] = sk;
        reinterpret_cast<float4*>(V + (size_t)grow * DIM)[tx] = sv;
    }
}

// ---------------- fused GT: softmax-normalized attention gather -------------
// Per row: loop1 computes per-head norm (ex recomputed in loop2), loop2
// accumulates (ex/norm)*V[col]. out[row] += result.
__global__ __launch_bounds__(256) void gt_fused(
    const int* __restrict__ cursor, const int* __restrict__ pcol,
    const float* __restrict__ Q, const float* __restrict__ K,
    const float* __restrict__ V, float* __restrict__ out) {
    int t = blockIdx.x * 256 + threadIdx.x;
    int row = t >> 4, l = t & 15;
    if (row >= NTOT) return;
    int s = (row == 0) ? 0 : cursor[row - 1];
    int e = cursor[row];
    float4 q = reinterpret_cast<const float4*>(Q)[(size_t)row * 16 + l];
    float norm = 0.f;
    for (int j = s; j < e; ++j) {
        int c = pcol[j];
        float4 k = reinterpret_cast<const float4*>(K)[(size_t)c * 16 + l];
        float p = q.x * k.x + q.y * k.y + q.z * k.z + q.w * k.w;
        p += __shfl_xor(p, 1);
        p += __shfl_xor(p, 2);
        p = fminf(10.f, fmaxf(-10.f, p));
        norm += expf(p);
    }
    float inv = 1.f / (norm + 1e-8f);
    float4 acc = {0.f, 0.f, 0.f, 0.f};
    for (int j = s; j < e; ++j) {
        int c = pcol[j];
        float4 k = reinterpret_cast<const float4*>(K)[(size_t)c * 16 + l];
        float p = q.x * k.x + q.y * k.y + q.z * k.z + q.w * k.w;
        p += __shfl_xor(p, 1);
        p += __shfl_xor(p, 2);
        p = fminf(10.f, fmaxf(-10.f, p));
        float a = expf(p) * inv;
        float4 v = reinterpret_cast<const float4*>(V)[(size_t)c * 16 + l];
        acc.x += a * v.x; acc.y += a * v.y; acc.z += a * v.z; acc.w += a * v.w;
    }
    float4 o = reinterpret_cast<float4*>(out)[(size_t)row * 16 + l];
    o.x += acc.x; o.y += acc.y; o.z += acc.z; o.w += acc.w;
    reinterpret_cast<float4*>(out)[(size_t)row * 16 + l] = o;
}

extern "C" void kernel_launch(void* const* d_in, const int* in_sizes, int n_in,
                              void* d_out, int out_size, void* d_ws, size_t ws_size,
                              hipStream_t stream) {
    const float* uE       = (const float*)d_in[0];
    const float* iE       = (const float*)d_in[1];
    const float* qT       = (const float*)d_in[2];
    const float* kT       = (const float*)d_in[3];
    const float* vT       = (const float*)d_in[4];
    const float* enc_vals = (const float*)d_in[5];
    const int*   enc_rows = (const int*)d_in[6];
    const int*   enc_cols = (const int*)d_in[7];
    const int*   dec_rows = (const int*)d_in[8];
    const int*   dec_cols = (const int*)d_in[9];
    float* out = (float*)d_out;

    const size_t ND = (size_t)NTOT * DIM;
    float* ws   = (float*)d_ws;
    float* emb1 = ws;
    float* emb2 = ws + ND;
    float* Q    = ws + 2 * ND;
    int*   cursorE = (int*)(ws + 3 * ND);
    int*   pcolE   = cursorE + NTOT;
    float* pvalE   = (float*)(pcolE + NEDGE);
    int*   cursorD = (int*)(pvalE + NEDGE);
    int*   pcolD   = cursorD + NTOT;
    int*   bsum    = pcolD + NEDGE;     // 512 ints temp
    float* K = emb1;   // reused after sum_kernel consumed emb1
    float* V = emb2;   // in-place over emb2 (qkv blocks read own rows first)

    const int EB  = (NEDGE + 255) / 256;        // 4688
    const int GB  = (NTOT * 16) / 256;          // 18750
    const int QB  = (NTOT + 63) / 64;           // 4688

    // --- build enc CSR ---
    hipMemsetAsync(cursorE, 0, NTOT * sizeof(int), stream);
    hist_kernel<<<EB, 256, 0, stream>>>(enc_rows, cursorE);
    scan1<<<NSCAN_BLK, 256, 0, stream>>>(cursorE, bsum);
    scan2<<<1, 512, 0, stream>>>(bsum);
    scan3<<<NSCAN_BLK, 256, 0, stream>>>(cursorE, bsum);
    scatter_enc<<<EB, 256, 0, stream>>>(enc_rows, enc_cols, enc_vals, cursorE, pcolE, pvalE);

    // --- build dec CSR ---
    hipMemsetAsync(cursorD, 0, NTOT * sizeof(int), stream);
    hist_kernel<<<EB, 256, 0, stream>>>(dec_rows, cursorD);
    scan1<<<NSCAN_BLK, 256, 0, stream>>>(cursorD, bsum);
    scan2<<<1, 512, 0, stream>>>(bsum);
    scan3<<<NSCAN_BLK, 256, 0, stream>>>(cursorD, bsum);
    scatter_dec<<<EB, 256, 0, stream>>>(dec_rows, dec_cols, cursorD, pcolD);

    // --- GCN layers (gather, no atomics) ---
    gcn_gather<<<GB, 256, 0, stream>>>(cursorE, pcolE, pvalE, uE, iE, emb1);
    gcn_gather<<<GB, 256, 0, stream>>>(cursorE, pcolE, pvalE, emb1, nullptr, emb2);

    // --- layer sum ---
    sum_kernel<<<GB, 256, 0, stream>>>(uE, iE, emb1, emb2, out);

    // --- QKV + fused graph transformer ---
    qkv_kernel<<<QB, 256, 0, stream>>>(emb2, qT, kT, vT, Q, K, V);
    gt_fused<<<GB, 256, 0, stream>>>(cursorD, pcolD, Q, K, V, out);
}

// Round 3
// 668.066 us; speedup vs baseline: 4.9630x; 1.0878x over previous
//
#include <hip/hip_runtime.h>
#include <math.h>

#define N_USERS 100000
#define NTOT    300000
#define NEDGE   1200000
#define DIM     64
#define SCAN_CHUNK 1024
#define NSCAN_BLK ((NTOT + SCAN_CHUNK - 1) / SCAN_CHUNK)   // 293

// Workspace layout (~247 MB):
//   [0, 2*ND)      : emb1 (layer-1 out; dead after gather2) -> reused as KV interleaved
//   [2*ND, 3*ND)   : emb2 (layer-2 out) -> overwritten in-place by Q in qkv
//   then CSR block : cursorE, cursorD (contiguous for one memset), pcolE, pvalE, pcolD, bsum

// ---------------- CSR build -------------------------------------------------
__global__ __launch_bounds__(256) void hist_kernel(const int* __restrict__ rows,
                                                   int* __restrict__ cnt) {
    int e = blockIdx.x * 256 + threadIdx.x;
    if (e < NEDGE) atomicAdd(&cnt[rows[e]], 1);
}

__global__ __launch_bounds__(256) void scan1(const int* __restrict__ cnt,
                                             int* __restrict__ bsum) {
    __shared__ int sh[256];
    int b = blockIdx.x, t = threadIdx.x;
    int base = b * SCAN_CHUNK + t * 4;
    int s = 0;
#pragma unroll
    for (int i = 0; i < 4; ++i) { int idx = base + i; if (idx < NTOT) s += cnt[idx]; }
    sh[t] = s; __syncthreads();
    for (int off = 1; off < 256; off <<= 1) {
        int x = (t >= off) ? sh[t - off] : 0; __syncthreads();
        sh[t] += x; __syncthreads();
    }
    if (t == 255) bsum[b] = sh[255];
}

__global__ __launch_bounds__(512) void scan2(int* __restrict__ bsum) {
    __shared__ int sh[512];
    int t = threadIdx.x;
    int v = (t < NSCAN_BLK) ? bsum[t] : 0;
    sh[t] = v; __syncthreads();
    for (int off = 1; off < 512; off <<= 1) {
        int x = (t >= off) ? sh[t - off] : 0; __syncthreads();
        sh[t] += x; __syncthreads();
    }
    if (t < NSCAN_BLK) bsum[t] = sh[t] - v;   // exclusive
}

__global__ __launch_bounds__(256) void scan3(int* __restrict__ cnt,
                                             const int* __restrict__ bsum) {
    __shared__ int sh[256];
    int b = blockIdx.x, t = threadIdx.x;
    int base = b * SCAN_CHUNK + t * 4;
    int c[4]; int s = 0;
#pragma unroll
    for (int i = 0; i < 4; ++i) { int idx = base + i; c[i] = (idx < NTOT) ? cnt[idx] : 0; s += c[i]; }
    sh[t] = s; __syncthreads();
    for (int off = 1; off < 256; off <<= 1) {
        int x = (t >= off) ? sh[t - off] : 0; __syncthreads();
        sh[t] += x; __syncthreads();
    }
    int excl = sh[t] - s + bsum[b];
#pragma unroll
    for (int i = 0; i < 4; ++i) {
        int idx = base + i;
        if (idx < NTOT) { cnt[idx] = excl; excl += c[i]; }
    }
}

__global__ __launch_bounds__(256) void scatter_enc(
    const int* __restrict__ rows, const int* __restrict__ cols,
    const float* __restrict__ vals, int* __restrict__ cursor,
    int* __restrict__ pcol, float* __restrict__ pval) {
    int e = blockIdx.x * 256 + threadIdx.x;
    if (e >= NEDGE) return;
    int pos = atomicAdd(&cursor[rows[e]], 1);
    pcol[pos] = cols[e];
    pval[pos] = vals[e];
}

__global__ __launch_bounds__(256) void scatter_dec(
    const int* __restrict__ rows, const int* __restrict__ cols,
    int* __restrict__ cursor, int* __restrict__ pcol) {
    int e = blockIdx.x * 256 + threadIdx.x;
    if (e >= NEDGE) return;
    int pos = atomicAdd(&cursor[rows[e]], 1);
    pcol[pos] = cols[e];
}

// ---------------- GCN layer 1: emb1[r] = sum val * emb0[col] ----------------
__global__ __launch_bounds__(256) void gcn_gather1(
    const int* __restrict__ cursor, const int* __restrict__ pcol,
    const float* __restrict__ pval, const float* __restrict__ uE,
    const float* __restrict__ iE, float* __restrict__ dst) {
    int t = blockIdx.x * 256 + threadIdx.x;
    int row = t >> 4, l = t & 15;
    if (row >= NTOT) return;
    int s = (row == 0) ? 0 : cursor[row - 1];
    int e = cursor[row];
    float4 acc = {0.f, 0.f, 0.f, 0.f};
    for (int j = s; j < e; ++j) {
        int c = pcol[j];
        float v = pval[j];
        const float* src = (c < N_USERS) ? uE + (size_t)c * DIM
                                         : iE + (size_t)(c - N_USERS) * DIM;
        float4 x = reinterpret_cast<const float4*>(src)[l];
        acc.x += v * x.x; acc.y += v * x.y; acc.z += v * x.z; acc.w += v * x.w;
    }
    reinterpret_cast<float4*>(dst)[(size_t)row * 16 + l] = acc;
}

// ---------------- GCN layer 2 + layer-sum fusion ----------------------------
// emb2[r] = sum val * emb1[col];  out[r] = emb0[r] + emb1[r] + emb2[r]
__global__ __launch_bounds__(256) void gcn_gather2(
    const int* __restrict__ cursor, const int* __restrict__ pcol,
    const float* __restrict__ pval, const float* __restrict__ emb1,
    const float* __restrict__ uE, const float* __restrict__ iE,
    float* __restrict__ emb2, float* __restrict__ out) {
    int t = blockIdx.x * 256 + threadIdx.x;
    int row = t >> 4, l = t & 15;
    if (row >= NTOT) return;
    int s = (row == 0) ? 0 : cursor[row - 1];
    int e = cursor[row];
    float4 acc = {0.f, 0.f, 0.f, 0.f};
    for (int j = s; j < e; ++j) {
        int c = pcol[j];
        float v = pval[j];
        float4 x = reinterpret_cast<const float4*>(emb1)[(size_t)c * 16 + l];
        acc.x += v * x.x; acc.y += v * x.y; acc.z += v * x.z; acc.w += v * x.w;
    }
    const float* e0p = (row < N_USERS) ? uE + (size_t)row * DIM
                                       : iE + (size_t)(row - N_USERS) * DIM;
    float4 e0 = reinterpret_cast<const float4*>(e0p)[l];
    float4 e1 = reinterpret_cast<const float4*>(emb1)[(size_t)row * 16 + l];
    reinterpret_cast<float4*>(emb2)[(size_t)row * 16 + l] = acc;
    float4 o;
    o.x = e0.x + e1.x + acc.x; o.y = e0.y + e1.y + acc.y;
    o.z = e0.z + e1.z + acc.z; o.w = e0.w + e1.w + acc.w;
    reinterpret_cast<float4*>(out)[(size_t)row * 16 + l] = o;
}

// ---------------- fused Q/K/V = emb2 @ {qT,kT,vT} ---------------------------
// Q written in-place over emb2 (block stages own rows in LDS first).
// K,V written interleaved: KV[row] = [K row (64f) | V row (64f)].
__global__ __launch_bounds__(256) void qkv_kernel(
    float* __restrict__ emb2, const float* __restrict__ qT,
    const float* __restrict__ kT, const float* __restrict__ vT,
    float* __restrict__ KV) {
    __shared__ float lds[4 * 4096];
    float* a_t = lds;
    float* bq = lds + 4096;
    float* bk = lds + 8192;
    float* bv = lds + 12288;
    int t = threadIdx.x;
    int R0 = blockIdx.x * 64;

    {
        const float4* q4 = reinterpret_cast<const float4*>(qT);
        const float4* k4 = reinterpret_cast<const float4*>(kT);
        const float4* v4 = reinterpret_cast<const float4*>(vT);
        float4* lq = reinterpret_cast<float4*>(bq);
        float4* lk = reinterpret_cast<float4*>(bk);
        float4* lv = reinterpret_cast<float4*>(bv);
#pragma unroll
        for (int k = 0; k < 4; ++k) {
            lq[t + k * 256] = q4[t + k * 256];
            lk[t + k * 256] = k4[t + k * 256];
            lv[t + k * 256] = v4[t + k * 256];
        }
    }
    {
        int r = t >> 2, qt = t & 3;
        int grow = R0 + r;
        const float4* src = reinterpret_cast<const float4*>(emb2 + (size_t)grow * DIM);
        bool ok = (grow < NTOT);
#pragma unroll
        for (int k = 0; k < 4; ++k) {
            float4 x;
            if (ok) x = src[qt * 4 + k];
            else { x.x = x.y = x.z = x.w = 0.f; }
            int i0 = qt * 16 + k * 4;
            a_t[(i0 + 0) * 64 + r] = x.x;
            a_t[(i0 + 1) * 64 + r] = x.y;
            a_t[(i0 + 2) * 64 + r] = x.z;
            a_t[(i0 + 3) * 64 + r] = x.w;
        }
    }
    __syncthreads();

    int ty = t >> 4, tx = t & 15;
    float cq[4][4] = {}, ck[4][4] = {}, cv[4][4] = {};
#pragma unroll 4
    for (int i = 0; i < 64; ++i) {
        float4 a = *reinterpret_cast<const float4*>(&a_t[i * 64 + ty * 4]);
        float4 q = *reinterpret_cast<const float4*>(&bq[i * 64 + tx * 4]);
        float4 k = *reinterpret_cast<const float4*>(&bk[i * 64 + tx * 4]);
        float4 v = *reinterpret_cast<const float4*>(&bv[i * 64 + tx * 4]);
        float av[4] = {a.x, a.y, a.z, a.w};
        float qv[4] = {q.x, q.y, q.z, q.w};
        float kv[4] = {k.x, k.y, k.z, k.w};
        float vv[4] = {v.x, v.y, v.z, v.w};
#pragma unroll
        for (int r = 0; r < 4; ++r) {
#pragma unroll
            for (int c = 0; c < 4; ++c) {
                cq[r][c] += av[r] * qv[c];
                ck[r][c] += av[r] * kv[c];
                cv[r][c] += av[r] * vv[c];
            }
        }
    }
    __syncthreads();

#pragma unroll
    for (int r = 0; r < 4; ++r) {
        int grow = R0 + ty * 4 + r;
        if (grow >= NTOT) continue;
        float4 sq, sk, sv;
        sq.x = cq[r][0]; sq.y = cq[r][1]; sq.z = cq[r][2]; sq.w = cq[r][3];
        sk.x = ck[r][0]; sk.y = ck[r][1]; sk.z = ck[r][2]; sk.w = ck[r][3];
        sv.x = cv[r][0]; sv.y = cv[r][1]; sv.z = cv[r][2]; sv.w = cv[r][3];
        reinterpret_cast<float4*>(emb2 + (size_t)grow * DIM)[tx] = sq;       // Q in-place
        reinterpret_cast<float4*>(KV + (size_t)grow * 128)[tx] = sk;         // K half
        reinterpret_cast<float4*>(KV + (size_t)grow * 128)[16 + tx] = sv;    // V half
    }
}

// ---------------- fused GT, single pass --------------------------------------
// out[row] += (sum_e ex * V[col_e]) / (sum_e ex + 1e-8)
__global__ __launch_bounds__(256) void gt_fused(
    const int* __restrict__ cursor, const int* __restrict__ pcol,
    const float* __restrict__ Q, const float* __restrict__ KV,
    float* __restrict__ out) {
    int t = blockIdx.x * 256 + threadIdx.x;
    int row = t >> 4, l = t & 15;
    if (row >= NTOT) return;
    int s = (row == 0) ? 0 : cursor[row - 1];
    int e = cursor[row];
    float4 q = reinterpret_cast<const float4*>(Q)[(size_t)row * 16 + l];
    float norm = 0.f;
    float4 acc = {0.f, 0.f, 0.f, 0.f};
    for (int j = s; j < e; ++j) {
        int c = pcol[j];
        const float4* kv = reinterpret_cast<const float4*>(KV) + (size_t)c * 32;
        float4 k = kv[l];
        float4 v = kv[16 + l];
        float p = q.x * k.x + q.y * k.y + q.z * k.z + q.w * k.w;
        p += __shfl_xor(p, 1);
        p += __shfl_xor(p, 2);
        p = fminf(10.f, fmaxf(-10.f, p));
        float ex = __expf(p);
        norm += ex;
        acc.x += ex * v.x; acc.y += ex * v.y; acc.z += ex * v.z; acc.w += ex * v.w;
    }
    float inv = 1.f / (norm + 1e-8f);
    float4 o = reinterpret_cast<float4*>(out)[(size_t)row * 16 + l];
    o.x += acc.x * inv; o.y += acc.y * inv;
    o.z += acc.z * inv; o.w += acc.w * inv;
    reinterpret_cast<float4*>(out)[(size_t)row * 16 + l] = o;
}

extern "C" void kernel_launch(void* const* d_in, const int* in_sizes, int n_in,
                              void* d_out, int out_size, void* d_ws, size_t ws_size,
                              hipStream_t stream) {
    const float* uE       = (const float*)d_in[0];
    const float* iE       = (const float*)d_in[1];
    const float* qT       = (const float*)d_in[2];
    const float* kT       = (const float*)d_in[3];
    const float* vT       = (const float*)d_in[4];
    const float* enc_vals = (const float*)d_in[5];
    const int*   enc_rows = (const int*)d_in[6];
    const int*   enc_cols = (const int*)d_in[7];
    const int*   dec_rows = (const int*)d_in[8];
    const int*   dec_cols = (const int*)d_in[9];
    float* out = (float*)d_out;

    const size_t ND = (size_t)NTOT * DIM;
    float* ws   = (float*)d_ws;
    float* emb1 = ws;                 // [0, ND)
    float* KV   = ws;                 // [0, 2*ND) — overwrites emb1/emb2-slot after they die
    float* emb2 = ws + 2 * ND;        // [2*ND, 3*ND) — becomes Q in-place
    int*   cursorE = (int*)(ws + 3 * ND);
    int*   cursorD = cursorE + NTOT;  // contiguous with cursorE (single memset)
    int*   pcolE   = cursorD + NTOT;
    float* pvalE   = (float*)(pcolE + NEDGE);
    int*   pcolD   = (int*)(pvalE + NEDGE);
    int*   bsum    = pcolD + NEDGE;   // 512 ints temp

    const int EB  = (NEDGE + 255) / 256;        // 4688
    const int GB  = (NTOT * 16) / 256;          // 18750
    const int QB  = (NTOT + 63) / 64;           // 4688

    // --- build both CSRs ---
    hipMemsetAsync(cursorE, 0, 2 * NTOT * sizeof(int), stream);
    hist_kernel<<<EB, 256, 0, stream>>>(enc_rows, cursorE);
    scan1<<<NSCAN_BLK, 256, 0, stream>>>(cursorE, bsum);
    scan2<<<1, 512, 0, stream>>>(bsum);
    scan3<<<NSCAN_BLK, 256, 0, stream>>>(cursorE, bsum);
    scatter_enc<<<EB, 256, 0, stream>>>(enc_rows, enc_cols, enc_vals, cursorE, pcolE, pvalE);

    hist_kernel<<<EB, 256, 0, stream>>>(dec_rows, cursorD);
    scan1<<<NSCAN_BLK, 256, 0, stream>>>(cursorD, bsum);
    scan2<<<1, 512, 0, stream>>>(bsum);
    scan3<<<NSCAN_BLK, 256, 0, stream>>>(cursorD, bsum);
    scatter_dec<<<EB, 256, 0, stream>>>(dec_rows, dec_cols, cursorD, pcolD);

    // --- GCN layers (layer 2 fused with layer-sum) ---
    gcn_gather1<<<GB, 256, 0, stream>>>(cursorE, pcolE, pvalE, uE, iE, emb1);
    gcn_gather2<<<GB, 256, 0, stream>>>(cursorE, pcolE, pvalE, emb1, uE, iE, emb2, out);

    // --- QKV (Q in-place over emb2; KV interleaved over dead emb1 region) ---
    qkv_kernel<<<QB, 256, 0, stream>>>(emb2, qT, kT, vT, KV);

    // --- fused single-pass graph transformer ---
    gt_fused<<<GB, 256, 0, stream>>>(cursorD, pcolD, emb2, KV, out);
}

// Round 4
// 641.038 us; speedup vs baseline: 5.1723x; 1.0422x over previous
//
#include <hip/hip_runtime.h>
#include <math.h>

#define N_USERS 100000
#define NTOT    300000
#define NEDGE   1200000
#define DIM     64
#define NM      (2 * NTOT)                      // unified count array length
#define SCAN_CHUNK 1024
#define NSB     ((NM + SCAN_CHUNK - 1) / SCAN_CHUNK)   // 586

typedef unsigned short ushort_t;
typedef unsigned int uint_t;

__device__ __forceinline__ float bf2f(ushort_t u) {
    return __uint_as_float(((uint_t)u) << 16);
}
__device__ __forceinline__ ushort_t f2bf(float x) {
    uint_t b = __float_as_uint(x);
    b += 0x7FFFu + ((b >> 16) & 1u);            // round-to-nearest-even
    return (ushort_t)(b >> 16);
}

// Workspace layout (floats-equivalent, ~247 MB):
//   emb2 (f32, ND) | emb0b (bf16, ND) | emb1b (bf16, ND) | KV (bf16, 2*ND)
//   cursor (2*NTOT int) | pcol (2*NEDGE int) | pval (NEDGE f32) | bsum (1024 int)

// ---------------- emb0 -> bf16 table ----------------------------------------
__global__ __launch_bounds__(256) void convert_emb0(
    const float* __restrict__ uE, const float* __restrict__ iE,
    ushort_t* __restrict__ emb0b) {
    int i = blockIdx.x * 256 + threadIdx.x;     // float4 index over ND/4
    if (i >= NTOT * 16) return;
    float4 x = (i < N_USERS * 16) ? reinterpret_cast<const float4*>(uE)[i]
                                  : reinterpret_cast<const float4*>(iE)[i - N_USERS * 16];
    ushort4 o;
    o.x = f2bf(x.x); o.y = f2bf(x.y); o.z = f2bf(x.z); o.w = f2bf(x.w);
    reinterpret_cast<ushort4*>(emb0b)[i] = o;
}

// ---------------- unified CSR build ------------------------------------------
__global__ __launch_bounds__(256) void hist2(
    const int* __restrict__ enc_rows, const int* __restrict__ dec_rows,
    int* __restrict__ cnt) {
    int e = blockIdx.x * 256 + threadIdx.x;
    if (e < NEDGE) atomicAdd(&cnt[enc_rows[e]], 1);
    else if (e < 2 * NEDGE) atomicAdd(&cnt[NTOT + dec_rows[e - NEDGE]], 1);
}

__global__ __launch_bounds__(256) void scan1(const int* __restrict__ cnt,
                                             int* __restrict__ bsum) {
    __shared__ int sh[256];
    int b = blockIdx.x, t = threadIdx.x;
    int base = b * SCAN_CHUNK + t * 4;
    int s = 0;
#pragma unroll
    for (int i = 0; i < 4; ++i) { int idx = base + i; if (idx < NM) s += cnt[idx]; }
    sh[t] = s; __syncthreads();
    for (int off = 1; off < 256; off <<= 1) {
        int x = (t >= off) ? sh[t - off] : 0; __syncthreads();
        sh[t] += x; __syncthreads();
    }
    if (t == 255) bsum[b] = sh[255];
}

__global__ __launch_bounds__(1024) void scan2(int* __restrict__ bsum) {
    __shared__ int sh[1024];
    int t = threadIdx.x;
    int v = (t < NSB) ? bsum[t] : 0;
    sh[t] = v; __syncthreads();
    for (int off = 1; off < 1024; off <<= 1) {
        int x = (t >= off) ? sh[t - off] : 0; __syncthreads();
        sh[t] += x; __syncthreads();
    }
    if (t < NSB) bsum[t] = sh[t] - v;           // exclusive
}

__global__ __launch_bounds__(256) void scan3(int* __restrict__ cnt,
                                             const int* __restrict__ bsum) {
    __shared__ int sh[256];
    int b = blockIdx.x, t = threadIdx.x;
    int base = b * SCAN_CHUNK + t * 4;
    int c[4]; int s = 0;
#pragma unroll
    for (int i = 0; i < 4; ++i) { int idx = base + i; c[i] = (idx < NM) ? cnt[idx] : 0; s += c[i]; }
    sh[t] = s; __syncthreads();
    for (int off = 1; off < 256; off <<= 1) {
        int x = (t >= off) ? sh[t - off] : 0; __syncthreads();
        sh[t] += x; __syncthreads();
    }
    int excl = sh[t] - s + bsum[b];
#pragma unroll
    for (int i = 0; i < 4; ++i) {
        int idx = base + i;
        if (idx < NM) { cnt[idx] = excl; excl += c[i]; }
    }
}

__global__ __launch_bounds__(256) void scatter2(
    const int* __restrict__ enc_rows, const int* __restrict__ enc_cols,
    const float* __restrict__ enc_vals, const int* __restrict__ dec_rows,
    const int* __restrict__ dec_cols, int* __restrict__ cursor,
    int* __restrict__ pcol, float* __restrict__ pval) {
    int e = blockIdx.x * 256 + threadIdx.x;
    if (e < NEDGE) {
        int pos = atomicAdd(&cursor[enc_rows[e]], 1);
        pcol[pos] = enc_cols[e];
        pval[pos] = enc_vals[e];
    } else if (e < 2 * NEDGE) {
        int i = e - NEDGE;
        int pos = atomicAdd(&cursor[NTOT + dec_rows[i]], 1);   // pos in [E, 2E)
        pcol[pos] = dec_cols[i];
    }
}

// ---------------- GCN layer 1: emb1b[r] = bf16( sum val * emb0b[col] ) ------
__global__ __launch_bounds__(256) void gcn_gather1(
    const int* __restrict__ cursor, const int* __restrict__ pcol,
    const float* __restrict__ pval, const ushort_t* __restrict__ emb0b,
    ushort_t* __restrict__ emb1b) {
    int t = blockIdx.x * 256 + threadIdx.x;
    int row = t >> 4, l = t & 15;
    if (row >= NTOT) return;
    int s = (row == 0) ? 0 : cursor[row - 1];
    int e = cursor[row];
    float4 acc = {0.f, 0.f, 0.f, 0.f};
    for (int j = s; j < e; ++j) {
        int c = pcol[j];
        float v = pval[j];
        ushort4 xb = reinterpret_cast<const ushort4*>(emb0b + (size_t)c * DIM)[l];
        acc.x += v * bf2f(xb.x); acc.y += v * bf2f(xb.y);
        acc.z += v * bf2f(xb.z); acc.w += v * bf2f(xb.w);
    }
    ushort4 o;
    o.x = f2bf(acc.x); o.y = f2bf(acc.y); o.z = f2bf(acc.z); o.w = f2bf(acc.w);
    reinterpret_cast<ushort4*>(emb1b)[(size_t)row * 16 + l] = o;
}

// ---------------- GCN layer 2 + layer-sum fusion -----------------------------
// emb2[r] = sum val * emb1b[col];  out[r] = emb0_f32[r] + emb1b[r] + emb2[r]
__global__ __launch_bounds__(256) void gcn_gather2(
    const int* __restrict__ cursor, const int* __restrict__ pcol,
    const float* __restrict__ pval, const ushort_t* __restrict__ emb1b,
    const float* __restrict__ uE, const float* __restrict__ iE,
    float* __restrict__ emb2, float* __restrict__ out) {
    int t = blockIdx.x * 256 + threadIdx.x;
    int row = t >> 4, l = t & 15;
    if (row >= NTOT) return;
    int s = (row == 0) ? 0 : cursor[row - 1];
    int e = cursor[row];
    float4 acc = {0.f, 0.f, 0.f, 0.f};
    for (int j = s; j < e; ++j) {
        int c = pcol[j];
        float v = pval[j];
        ushort4 xb = reinterpret_cast<const ushort4*>(emb1b + (size_t)c * DIM)[l];
        acc.x += v * bf2f(xb.x); acc.y += v * bf2f(xb.y);
        acc.z += v * bf2f(xb.z); acc.w += v * bf2f(xb.w);
    }
    const float* e0p = (row < N_USERS) ? uE + (size_t)row * DIM
                                       : iE + (size_t)(row - N_USERS) * DIM;
    float4 e0 = reinterpret_cast<const float4*>(e0p)[l];
    ushort4 e1b = reinterpret_cast<const ushort4*>(emb1b)[(size_t)row * 16 + l];
    reinterpret_cast<float4*>(emb2)[(size_t)row * 16 + l] = acc;
    float4 o;
    o.x = e0.x + bf2f(e1b.x) + acc.x; o.y = e0.y + bf2f(e1b.y) + acc.y;
    o.z = e0.z + bf2f(e1b.z) + acc.z; o.w = e0.w + bf2f(e1b.w) + acc.w;
    reinterpret_cast<float4*>(out)[(size_t)row * 16 + l] = o;
}

// ---------------- fused Q/K/V = emb2 @ {qT,kT,vT} ----------------------------
// Q (f32) in-place over emb2; K,V interleaved bf16: KV[row] = [K 64bf | V 64bf]
__global__ __launch_bounds__(256) void qkv_kernel(
    float* __restrict__ emb2, const float* __restrict__ qT,
    const float* __restrict__ kT, const float* __restrict__ vT,
    ushort_t* __restrict__ KV) {
    __shared__ float lds[4 * 4096];
    float* a_t = lds;
    float* bq = lds + 4096;
    float* bk = lds + 8192;
    float* bv = lds + 12288;
    int t = threadIdx.x;
    int R0 = blockIdx.x * 64;

    {
        const float4* q4 = reinterpret_cast<const float4*>(qT);
        const float4* k4 = reinterpret_cast<const float4*>(kT);
        const float4* v4 = reinterpret_cast<const float4*>(vT);
        float4* lq = reinterpret_cast<float4*>(bq);
        float4* lk = reinterpret_cast<float4*>(bk);
        float4* lv = reinterpret_cast<float4*>(bv);
#pragma unroll
        for (int k = 0; k < 4; ++k) {
            lq[t + k * 256] = q4[t + k * 256];
            lk[t + k * 256] = k4[t + k * 256];
            lv[t + k * 256] = v4[t + k * 256];
        }
    }
    {
        int r = t >> 2, qt = t & 3;
        int grow = R0 + r;
        const float4* src = reinterpret_cast<const float4*>(emb2 + (size_t)grow * DIM);
        bool ok = (grow < NTOT);
#pragma unroll
        for (int k = 0; k < 4; ++k) {
            float4 x;
            if (ok) x = src[qt * 4 + k];
            else { x.x = x.y = x.z = x.w = 0.f; }
            int i0 = qt * 16 + k * 4;
            a_t[(i0 + 0) * 64 + r] = x.x;
            a_t[(i0 + 1) * 64 + r] = x.y;
            a_t[(i0 + 2) * 64 + r] = x.z;
            a_t[(i0 + 3) * 64 + r] = x.w;
        }
    }
    __syncthreads();

    int ty = t >> 4, tx = t & 15;
    float cq[4][4] = {}, ck[4][4] = {}, cv[4][4] = {};
#pragma unroll 4
    for (int i = 0; i < 64; ++i) {
        float4 a = *reinterpret_cast<const float4*>(&a_t[i * 64 + ty * 4]);
        float4 q = *reinterpret_cast<const float4*>(&bq[i * 64 + tx * 4]);
        float4 k = *reinterpret_cast<const float4*>(&bk[i * 64 + tx * 4]);
        float4 v = *reinterpret_cast<const float4*>(&bv[i * 64 + tx * 4]);
        float av[4] = {a.x, a.y, a.z, a.w};
        float qv[4] = {q.x, q.y, q.z, q.w};
        float kv[4] = {k.x, k.y, k.z, k.w};
        float vv[4] = {v.x, v.y, v.z, v.w};
#pragma unroll
        for (int r = 0; r < 4; ++r) {
#pragma unroll
            for (int c = 0; c < 4; ++c) {
                cq[r][c] += av[r] * qv[c];
                ck[r][c] += av[r] * kv[c];
                cv[r][c] += av[r] * vv[c];
            }
        }
    }
    __syncthreads();

#pragma unroll
    for (int r = 0; r < 4; ++r) {
        int grow = R0 + ty * 4 + r;
        if (grow >= NTOT) continue;
        float4 sq;
        sq.x = cq[r][0]; sq.y = cq[r][1]; sq.z = cq[r][2]; sq.w = cq[r][3];
        ushort4 skb, svb;
        skb.x = f2bf(ck[r][0]); skb.y = f2bf(ck[r][1]);
        skb.z = f2bf(ck[r][2]); skb.w = f2bf(ck[r][3]);
        svb.x = f2bf(cv[r][0]); svb.y = f2bf(cv[r][1]);
        svb.z = f2bf(cv[r][2]); svb.w = f2bf(cv[r][3]);
        reinterpret_cast<float4*>(emb2 + (size_t)grow * DIM)[tx] = sq;           // Q
        reinterpret_cast<ushort4*>(KV + (size_t)grow * 128)[tx] = skb;           // K half
        reinterpret_cast<ushort4*>(KV + (size_t)grow * 128)[16 + tx] = svb;      // V half
    }
}

// ---------------- fused GT, single pass, bf16 KV ------------------------------
__global__ __launch_bounds__(256) void gt_fused(
    const int* __restrict__ cursor, const int* __restrict__ pcol,
    const float* __restrict__ Q, const ushort_t* __restrict__ KV,
    float* __restrict__ out) {
    int t = blockIdx.x * 256 + threadIdx.x;
    int row = t >> 4, l = t & 15;
    if (row >= NTOT) return;
    int s = cursor[NTOT + row - 1];             // row 0 -> cursor[NTOT-1] == NEDGE
    int e = cursor[NTOT + row];
    float4 q = reinterpret_cast<const float4*>(Q)[(size_t)row * 16 + l];
    float norm = 0.f;
    float4 acc = {0.f, 0.f, 0.f, 0.f};
    for (int j = s; j < e; ++j) {
        int c = pcol[j];
        const ushort_t* kvrow = KV + (size_t)c * 128;
        ushort4 kb = reinterpret_cast<const ushort4*>(kvrow)[l];
        ushort4 vb = reinterpret_cast<const ushort4*>(kvrow)[16 + l];
        float p = q.x * bf2f(kb.x) + q.y * bf2f(kb.y)
                + q.z * bf2f(kb.z) + q.w * bf2f(kb.w);
        p += __shfl_xor(p, 1);
        p += __shfl_xor(p, 2);
        p = fminf(10.f, fmaxf(-10.f, p));
        float ex = __expf(p);
        norm += ex;
        acc.x += ex * bf2f(vb.x); acc.y += ex * bf2f(vb.y);
        acc.z += ex * bf2f(vb.z); acc.w += ex * bf2f(vb.w);
    }
    float inv = 1.f / (norm + 1e-8f);
    float4 o = reinterpret_cast<float4*>(out)[(size_t)row * 16 + l];
    o.x += acc.x * inv; o.y += acc.y * inv;
    o.z += acc.z * inv; o.w += acc.w * inv;
    reinterpret_cast<float4*>(out)[(size_t)row * 16 + l] = o;
}

extern "C" void kernel_launch(void* const* d_in, const int* in_sizes, int n_in,
                              void* d_out, int out_size, void* d_ws, size_t ws_size,
                              hipStream_t stream) {
    const float* uE       = (const float*)d_in[0];
    const float* iE       = (const float*)d_in[1];
    const float* qT       = (const float*)d_in[2];
    const float* kT       = (const float*)d_in[3];
    const float* vT       = (const float*)d_in[4];
    const float* enc_vals = (const float*)d_in[5];
    const int*   enc_rows = (const int*)d_in[6];
    const int*   enc_cols = (const int*)d_in[7];
    const int*   dec_rows = (const int*)d_in[8];
    const int*   dec_cols = (const int*)d_in[9];
    float* out = (float*)d_out;

    const size_t ND = (size_t)NTOT * DIM;       // 19.2M
    float*    ws    = (float*)d_ws;
    float*    emb2  = ws;                                   // f32, ND  (becomes Q)
    ushort_t* emb0b = (ushort_t*)(ws + ND);                 // bf16, ND
    ushort_t* emb1b = emb0b + ND;                           // bf16, ND
    ushort_t* KV    = emb1b + ND;                           // bf16, 2*ND
    int*      cursor= (int*)(KV + 2 * ND);                  // 2*NTOT
    int*      pcol  = cursor + NM;                          // 2*NEDGE
    float*    pval  = (float*)(pcol + 2 * NEDGE);           // NEDGE
    int*      bsum  = (int*)(pval + NEDGE);                 // 1024

    const int EB2 = (2 * NEDGE + 255) / 256;    // 9375
    const int GB  = (NTOT * 16) / 256;          // 18750
    const int QB  = (NTOT + 63) / 64;           // 4688

    hipMemsetAsync(cursor, 0, NM * sizeof(int), stream);
    convert_emb0<<<GB, 256, 0, stream>>>(uE, iE, emb0b);
    hist2<<<EB2, 256, 0, stream>>>(enc_rows, dec_rows, cursor);
    scan1<<<NSB, 256, 0, stream>>>(cursor, bsum);
    scan2<<<1, 1024, 0, stream>>>(bsum);
    scan3<<<NSB, 256, 0, stream>>>(cursor, bsum);
    scatter2<<<EB2, 256, 0, stream>>>(enc_rows, enc_cols, enc_vals,
                                      dec_rows, dec_cols, cursor, pcol, pval);

    gcn_gather1<<<GB, 256, 0, stream>>>(cursor, pcol, pval, emb0b, emb1b);
    gcn_gather2<<<GB, 256, 0, stream>>>(cursor, pcol, pval, emb1b, uE, iE, emb2, out);

    qkv_kernel<<<QB, 256, 0, stream>>>(emb2, qT, kT, vT, KV);
    gt_fused<<<GB, 256, 0, stream>>>(cursor, pcol, emb2, KV, out);
}

// Round 5
// 584.963 us; speedup vs baseline: 5.6681x; 1.0959x over previous
//
#include <hip/hip_runtime.h>
#include <math.h>

#define N_USERS 100000
#define NTOT    300000
#define NEDGE   1200000
#define DIM     64
#define NM      (2 * NTOT)                      // unified count array length
#define PART    75000                           // rows per partition (NM/8)
#define SCAN_CHUNK 1024
#define NSB     ((NM + SCAN_CHUNK - 1) / SCAN_CHUNK)   // 586

typedef unsigned short ushort_t;
typedef unsigned int uint_t;

__device__ __forceinline__ float bf2f(ushort_t u) {
    return __uint_as_float(((uint_t)u) << 16);
}
__device__ __forceinline__ ushort_t f2bf(float x) {
    uint_t b = __float_as_uint(x);
    b += 0x7FFFu + ((b >> 16) & 1u);            // round-to-nearest-even
    return (ushort_t)(b >> 16);
}

// Workspace (~247 MB):
//   emb2 (f32, ND) | emb0b (bf16, ND) | emb1b (bf16, ND) | KV (bf16, 2*ND)
//   cursor (2*NTOT int) | penc (int2[E]) | pdec (int[E]) | bsum (1024 int)

// ---------------- emb0 -> bf16 table ----------------------------------------
__global__ __launch_bounds__(256) void convert_emb0(
    const float* __restrict__ uE, const float* __restrict__ iE,
    ushort_t* __restrict__ emb0b) {
    int i = blockIdx.x * 256 + threadIdx.x;
    if (i >= NTOT * 16) return;
    float4 x = (i < N_USERS * 16) ? reinterpret_cast<const float4*>(uE)[i]
                                  : reinterpret_cast<const float4*>(iE)[i - N_USERS * 16];
    ushort4 o;
    o.x = f2bf(x.x); o.y = f2bf(x.y); o.z = f2bf(x.z); o.w = f2bf(x.w);
    reinterpret_cast<ushort4*>(emb0b)[i] = o;
}

// ---------------- XCD-partitioned histogram ----------------------------------
// Partition p = blockIdx%8 handles rows [base, base+PART) of enc (p<4) or
// dec (p>=4). blockIdx%8 round-robins over XCDs -> counter slice is L2-local.
__global__ __launch_bounds__(256) void hist_part(
    const int* __restrict__ enc_rows, const int* __restrict__ dec_rows,
    int* __restrict__ cnt) {
    int pid = blockIdx.x & 7;
    const int* rows = (pid < 4) ? enc_rows : dec_rows;
    int base = (pid & 3) * PART;
    int coff = (pid < 4) ? 0 : NTOT;
    int nb = gridDim.x >> 3;
    int stride = nb * 256;
    for (int e = (blockIdx.x >> 3) * 256 + threadIdx.x; e < NEDGE; e += stride) {
        int r = rows[e];
        if ((unsigned)(r - base) < (unsigned)PART) atomicAdd(&cnt[coff + r], 1);
    }
}

// ---------------- scan (3-kernel exclusive prefix over NM) -------------------
__global__ __launch_bounds__(256) void scan1(const int* __restrict__ cnt,
                                             int* __restrict__ bsum) {
    __shared__ int sh[256];
    int b = blockIdx.x, t = threadIdx.x;
    int base = b * SCAN_CHUNK + t * 4;
    int s = 0;
#pragma unroll
    for (int i = 0; i < 4; ++i) { int idx = base + i; if (idx < NM) s += cnt[idx]; }
    sh[t] = s; __syncthreads();
    for (int off = 1; off < 256; off <<= 1) {
        int x = (t >= off) ? sh[t - off] : 0; __syncthreads();
        sh[t] += x; __syncthreads();
    }
    if (t == 255) bsum[b] = sh[255];
}

__global__ __launch_bounds__(1024) void scan2(int* __restrict__ bsum) {
    __shared__ int sh[1024];
    int t = threadIdx.x;
    int v = (t < NSB) ? bsum[t] : 0;
    sh[t] = v; __syncthreads();
    for (int off = 1; off < 1024; off <<= 1) {
        int x = (t >= off) ? sh[t - off] : 0; __syncthreads();
        sh[t] += x; __syncthreads();
    }
    if (t < NSB) bsum[t] = sh[t] - v;           // exclusive
}

__global__ __launch_bounds__(256) void scan3(int* __restrict__ cnt,
                                             const int* __restrict__ bsum) {
    __shared__ int sh[256];
    int b = blockIdx.x, t = threadIdx.x;
    int base = b * SCAN_CHUNK + t * 4;
    int c[4]; int s = 0;
#pragma unroll
    for (int i = 0; i < 4; ++i) { int idx = base + i; c[i] = (idx < NM) ? cnt[idx] : 0; s += c[i]; }
    sh[t] = s; __syncthreads();
    for (int off = 1; off < 256; off <<= 1) {
        int x = (t >= off) ? sh[t - off] : 0; __syncthreads();
        sh[t] += x; __syncthreads();
    }
    int excl = sh[t] - s + bsum[b];
#pragma unroll
    for (int i = 0; i < 4; ++i) {
        int idx = base + i;
        if (idx < NM) { cnt[idx] = excl; excl += c[i]; }
    }
}

// ---------------- XCD-partitioned scatter -------------------------------------
// Same partitioning as hist_part: partition p's CSR slice (~2.4 MB) is written
// only by XCD p -> L2 accumulates full lines -> HBM writes = useful bytes.
__global__ __launch_bounds__(256) void scatter_part(
    const int* __restrict__ enc_rows, const int* __restrict__ enc_cols,
    const float* __restrict__ enc_vals, const int* __restrict__ dec_rows,
    const int* __restrict__ dec_cols, int* __restrict__ cursor,
    int2* __restrict__ penc, int* __restrict__ pdec) {
    int pid = blockIdx.x & 7;
    int nb = gridDim.x >> 3;
    int stride = nb * 256;
    int e0 = (blockIdx.x >> 3) * 256 + threadIdx.x;
    if (pid < 4) {
        int base = pid * PART;
        for (int e = e0; e < NEDGE; e += stride) {
            int r = enc_rows[e];
            if ((unsigned)(r - base) < (unsigned)PART) {
                int pos = atomicAdd(&cursor[r], 1);
                int2 cv;
                cv.x = enc_cols[e];
                cv.y = __float_as_int(enc_vals[e]);
                penc[pos] = cv;
            }
        }
    } else {
        int base = (pid - 4) * PART;
        for (int e = e0; e < NEDGE; e += stride) {
            int r = dec_rows[e];
            if ((unsigned)(r - base) < (unsigned)PART) {
                int pos = atomicAdd(&cursor[NTOT + r], 1);
                pdec[pos - NEDGE] = dec_cols[e];
            }
        }
    }
}

// ---------------- GCN layer 1: emb1b[r] = bf16( sum val * emb0b[col] ) ------
__global__ __launch_bounds__(256) void gcn_gather1(
    const int* __restrict__ cursor, const int2* __restrict__ penc,
    const ushort_t* __restrict__ emb0b, ushort_t* __restrict__ emb1b) {
    int t = blockIdx.x * 256 + threadIdx.x;
    int row = t >> 4, l = t & 15;
    if (row >= NTOT) return;
    int s = (row == 0) ? 0 : cursor[row - 1];
    int e = cursor[row];
    float4 acc = {0.f, 0.f, 0.f, 0.f};
    for (int j = s; j < e; ++j) {
        int2 cv = penc[j];
        float v = __int_as_float(cv.y);
        ushort4 xb = reinterpret_cast<const ushort4*>(emb0b + (size_t)cv.x * DIM)[l];
        acc.x += v * bf2f(xb.x); acc.y += v * bf2f(xb.y);
        acc.z += v * bf2f(xb.z); acc.w += v * bf2f(xb.w);
    }
    ushort4 o;
    o.x = f2bf(acc.x); o.y = f2bf(acc.y); o.z = f2bf(acc.z); o.w = f2bf(acc.w);
    reinterpret_cast<ushort4*>(emb1b)[(size_t)row * 16 + l] = o;
}

// ---------------- GCN layer 2 + layer-sum fusion -----------------------------
__global__ __launch_bounds__(256) void gcn_gather2(
    const int* __restrict__ cursor, const int2* __restrict__ penc,
    const ushort_t* __restrict__ emb1b, const float* __restrict__ uE,
    const float* __restrict__ iE, float* __restrict__ emb2,
    float* __restrict__ out) {
    int t = blockIdx.x * 256 + threadIdx.x;
    int row = t >> 4, l = t & 15;
    if (row >= NTOT) return;
    int s = (row == 0) ? 0 : cursor[row - 1];
    int e = cursor[row];
    float4 acc = {0.f, 0.f, 0.f, 0.f};
    for (int j = s; j < e; ++j) {
        int2 cv = penc[j];
        float v = __int_as_float(cv.y);
        ushort4 xb = reinterpret_cast<const ushort4*>(emb1b + (size_t)cv.x * DIM)[l];
        acc.x += v * bf2f(xb.x); acc.y += v * bf2f(xb.y);
        acc.z += v * bf2f(xb.z); acc.w += v * bf2f(xb.w);
    }
    const float* e0p = (row < N_USERS) ? uE + (size_t)row * DIM
                                       : iE + (size_t)(row - N_USERS) * DIM;
    float4 e0 = reinterpret_cast<const float4*>(e0p)[l];
    ushort4 e1b = reinterpret_cast<const ushort4*>(emb1b)[(size_t)row * 16 + l];
    reinterpret_cast<float4*>(emb2)[(size_t)row * 16 + l] = acc;
    float4 o;
    o.x = e0.x + bf2f(e1b.x) + acc.x; o.y = e0.y + bf2f(e1b.y) + acc.y;
    o.z = e0.z + bf2f(e1b.z) + acc.z; o.w = e0.w + bf2f(e1b.w) + acc.w;
    reinterpret_cast<float4*>(out)[(size_t)row * 16 + l] = o;
}

// ---------------- fused Q/K/V = emb2 @ {qT,kT,vT} ----------------------------
__global__ __launch_bounds__(256) void qkv_kernel(
    float* __restrict__ emb2, const float* __restrict__ qT,
    const float* __restrict__ kT, const float* __restrict__ vT,
    ushort_t* __restrict__ KV) {
    __shared__ float lds[4 * 4096];
    float* a_t = lds;
    float* bq = lds + 4096;
    float* bk = lds + 8192;
    float* bv = lds + 12288;
    int t = threadIdx.x;
    int R0 = blockIdx.x * 64;

    {
        const float4* q4 = reinterpret_cast<const float4*>(qT);
        const float4* k4 = reinterpret_cast<const float4*>(kT);
        const float4* v4 = reinterpret_cast<const float4*>(vT);
        float4* lq = reinterpret_cast<float4*>(bq);
        float4* lk = reinterpret_cast<float4*>(bk);
        float4* lv = reinterpret_cast<float4*>(bv);
#pragma unroll
        for (int k = 0; k < 4; ++k) {
            lq[t + k * 256] = q4[t + k * 256];
            lk[t + k * 256] = k4[t + k * 256];
            lv[t + k * 256] = v4[t + k * 256];
        }
    }
    {
        int r = t >> 2, qt = t & 3;
        int grow = R0 + r;
        const float4* src = reinterpret_cast<const float4*>(emb2 + (size_t)grow * DIM);
        bool ok = (grow < NTOT);
#pragma unroll
        for (int k = 0; k < 4; ++k) {
            float4 x;
            if (ok) x = src[qt * 4 + k];
            else { x.x = x.y = x.z = x.w = 0.f; }
            int i0 = qt * 16 + k * 4;
            a_t[(i0 + 0) * 64 + r] = x.x;
            a_t[(i0 + 1) * 64 + r] = x.y;
            a_t[(i0 + 2) * 64 + r] = x.z;
            a_t[(i0 + 3) * 64 + r] = x.w;
        }
    }
    __syncthreads();

    int ty = t >> 4, tx = t & 15;
    float cq[4][4] = {}, ck[4][4] = {}, cv[4][4] = {};
#pragma unroll 4
    for (int i = 0; i < 64; ++i) {
        float4 a = *reinterpret_cast<const float4*>(&a_t[i * 64 + ty * 4]);
        float4 q = *reinterpret_cast<const float4*>(&bq[i * 64 + tx * 4]);
        float4 k = *reinterpret_cast<const float4*>(&bk[i * 64 + tx * 4]);
        float4 v = *reinterpret_cast<const float4*>(&bv[i * 64 + tx * 4]);
        float av[4] = {a.x, a.y, a.z, a.w};
        float qv[4] = {q.x, q.y, q.z, q.w};
        float kv[4] = {k.x, k.y, k.z, k.w};
        float vv[4] = {v.x, v.y, v.z, v.w};
#pragma unroll
        for (int r = 0; r < 4; ++r) {
#pragma unroll
            for (int c = 0; c < 4; ++c) {
                cq[r][c] += av[r] * qv[c];
                ck[r][c] += av[r] * kv[c];
                cv[r][c] += av[r] * vv[c];
            }
        }
    }
    __syncthreads();

#pragma unroll
    for (int r = 0; r < 4; ++r) {
        int grow = R0 + ty * 4 + r;
        if (grow >= NTOT) continue;
        float4 sq;
        sq.x = cq[r][0]; sq.y = cq[r][1]; sq.z = cq[r][2]; sq.w = cq[r][3];
        ushort4 skb, svb;
        skb.x = f2bf(ck[r][0]); skb.y = f2bf(ck[r][1]);
        skb.z = f2bf(ck[r][2]); skb.w = f2bf(ck[r][3]);
        svb.x = f2bf(cv[r][0]); svb.y = f2bf(cv[r][1]);
        svb.z = f2bf(cv[r][2]); svb.w = f2bf(cv[r][3]);
        reinterpret_cast<float4*>(emb2 + (size_t)grow * DIM)[tx] = sq;           // Q
        reinterpret_cast<ushort4*>(KV + (size_t)grow * 128)[tx] = skb;           // K
        reinterpret_cast<ushort4*>(KV + (size_t)grow * 128)[16 + tx] = svb;      // V
    }
}

// ---------------- fused GT, single pass, bf16 KV ------------------------------
__global__ __launch_bounds__(256) void gt_fused(
    const int* __restrict__ cursor, const int* __restrict__ pdec,
    const float* __restrict__ Q, const ushort_t* __restrict__ KV,
    float* __restrict__ out) {
    int t = blockIdx.x * 256 + threadIdx.x;
    int row = t >> 4, l = t & 15;
    if (row >= NTOT) return;
    int s = cursor[NTOT + row - 1] - NEDGE;     // row 0 -> cursor[NTOT-1]==NEDGE -> 0
    int e = cursor[NTOT + row] - NEDGE;
    float4 q = reinterpret_cast<const float4*>(Q)[(size_t)row * 16 + l];
    float norm = 0.f;
    float4 acc = {0.f, 0.f, 0.f, 0.f};
    for (int j = s; j < e; ++j) {
        int c = pdec[j];
        const ushort_t* kvrow = KV + (size_t)c * 128;
        ushort4 kb = reinterpret_cast<const ushort4*>(kvrow)[l];
        ushort4 vb = reinterpret_cast<const ushort4*>(kvrow)[16 + l];
        float p = q.x * bf2f(kb.x) + q.y * bf2f(kb.y)
                + q.z * bf2f(kb.z) + q.w * bf2f(kb.w);
        p += __shfl_xor(p, 1);
        p += __shfl_xor(p, 2);
        p = fminf(10.f, fmaxf(-10.f, p));
        float ex = __expf(p);
        norm += ex;
        acc.x += ex * bf2f(vb.x); acc.y += ex * bf2f(vb.y);
        acc.z += ex * bf2f(vb.z); acc.w += ex * bf2f(vb.w);
    }
    float inv = 1.f / (norm + 1e-8f);
    float4 o = reinterpret_cast<float4*>(out)[(size_t)row * 16 + l];
    o.x += acc.x * inv; o.y += acc.y * inv;
    o.z += acc.z * inv; o.w += acc.w * inv;
    reinterpret_cast<float4*>(out)[(size_t)row * 16 + l] = o;
}

extern "C" void kernel_launch(void* const* d_in, const int* in_sizes, int n_in,
                              void* d_out, int out_size, void* d_ws, size_t ws_size,
                              hipStream_t stream) {
    const float* uE       = (const float*)d_in[0];
    const float* iE       = (const float*)d_in[1];
    const float* qT       = (const float*)d_in[2];
    const float* kT       = (const float*)d_in[3];
    const float* vT       = (const float*)d_in[4];
    const float* enc_vals = (const float*)d_in[5];
    const int*   enc_rows = (const int*)d_in[6];
    const int*   enc_cols = (const int*)d_in[7];
    const int*   dec_rows = (const int*)d_in[8];
    const int*   dec_cols = (const int*)d_in[9];
    float* out = (float*)d_out;

    const size_t ND = (size_t)NTOT * DIM;       // 19.2M
    float*    ws    = (float*)d_ws;
    float*    emb2  = ws;                                   // f32, ND  (becomes Q)
    ushort_t* emb0b = (ushort_t*)(ws + ND);                 // bf16, ND
    ushort_t* emb1b = emb0b + ND;                           // bf16, ND
    ushort_t* KV    = emb1b + ND;                           // bf16, 2*ND
    int*      cursor= (int*)(KV + 2 * ND);                  // 2*NTOT
    int2*     penc  = (int2*)(cursor + NM);                 // NEDGE int2
    int*      pdec  = (int*)(penc + NEDGE);                 // NEDGE int
    int*      bsum  = pdec + NEDGE;                         // 1024

    const int GB  = (NTOT * 16) / 256;          // 18750
    const int QB  = (NTOT + 63) / 64;           // 4688
    const int PB  = 2048;                       // 8 partitions x 256 blocks

    hipMemsetAsync(cursor, 0, NM * sizeof(int), stream);
    convert_emb0<<<GB, 256, 0, stream>>>(uE, iE, emb0b);
    hist_part<<<PB, 256, 0, stream>>>(enc_rows, dec_rows, cursor);
    scan1<<<NSB, 256, 0, stream>>>(cursor, bsum);
    scan2<<<1, 1024, 0, stream>>>(bsum);
    scan3<<<NSB, 256, 0, stream>>>(cursor, bsum);
    scatter_part<<<PB, 256, 0, stream>>>(enc_rows, enc_cols, enc_vals,
                                         dec_rows, dec_cols, cursor, penc, pdec);

    gcn_gather1<<<GB, 256, 0, stream>>>(cursor, penc, emb0b, emb1b);
    gcn_gather2<<<GB, 256, 0, stream>>>(cursor, penc, emb1b, uE, iE, emb2, out);

    qkv_kernel<<<QB, 256, 0, stream>>>(emb2, qT, kT, vT, KV);
    gt_fused<<<GB, 256, 0, stream>>>(cursor, pdec, emb2, KV, out);
}